// Round 3
// baseline (1119.064 us; speedup 1.0000x reference)
//
#include <hip/hip_runtime.h>
#include <hip/hip_bf16.h>
#include <stdint.h>
#include <stddef.h>

typedef __bf16 bf16;
typedef __bf16 bf16x8 __attribute__((ext_vector_type(8)));
typedef __bf16 bf16x4 __attribute__((ext_vector_type(4)));
typedef float f32x4 __attribute__((ext_vector_type(4)));

#define HID 1024
#define IDIM 2048
#define NE 8
#define NTOK 4096
#define NSLOT 12800
#define SH_BASE 8704
#define MAX_TILES 200

// ---- workspace byte offsets ----
#define WS_META    0
#define WS_PERM    4096              // u32[12800]
#define WS_TOKE    55296             // i32[8192]
#define WS_TOKW    88064             // f32[8192]
#define WS_SLOTOF  120832            // u32[8192]
#define WS_GATET   153600            // bf16[8][2048][1024]
#define WS_UPT     33708032
#define WS_DOWNT   67262464          // bf16[8][1024][2048]
#define WS_SGT     100816896         // bf16[2048][1024]
#define WS_SUT     105011200
#define WS_SDT     109205504         // bf16[1024][2048]
#define WS_ACT     113399808         // bf16[12800][2048]
#define WS_DOUT    165828608         // bf16[12800][1024]

// meta u32-index layout
#define M_CNT 0
#define M_CUR 8
#define M_PSUM 16
#define M_ZSUM 24
#define M_AOFF 32
#define M_NTILE 48
#define M_TE 64
#define M_TB 320

#define OUT_AUX 4194304
#define OUT_Z   4194305
#define OUT_LG  4194306

__device__ __forceinline__ int imin(int a, int b) { return a < b ? a : b; }

__global__ void zero_kernel(uint32_t* meta) {
    if (threadIdx.x < 32) meta[threadIdx.x] = 0;
}

// one wave per token; all f32
__global__ __launch_bounds__(256) void router_kernel(
    const float* __restrict__ x, const float* __restrict__ rw,
    float* __restrict__ out, uint32_t* meta, int* tok_e, float* tok_w)
{
    int lane = threadIdx.x & 63, wv = threadIdx.x >> 6;
    int t = blockIdx.x * 4 + wv;
    float acc[NE];
#pragma unroll
    for (int e = 0; e < NE; e++) acc[e] = 0.f;
#pragma unroll
    for (int it = 0; it < 4; it++) {
        int h0 = (lane + it * 64) * 4;
        f32x4 xv = *(const f32x4*)&x[(size_t)t * HID + h0];
#pragma unroll
        for (int j = 0; j < 4; j++) {
            float xf = xv[j];
            const float* wrow = rw + (size_t)(h0 + j) * NE;
            f32x4 w0 = *(const f32x4*)wrow;
            f32x4 w1 = *(const f32x4*)(wrow + 4);
#pragma unroll
            for (int e = 0; e < 4; e++) { acc[e] += xf * w0[e]; acc[e + 4] += xf * w1[e]; }
        }
    }
#pragma unroll
    for (int off = 32; off >= 1; off >>= 1)
#pragma unroll
        for (int e = 0; e < NE; e++) acc[e] += __shfl_xor(acc[e], off);

    if (lane == 0) {
        float mx = acc[0];
        for (int e = 1; e < NE; e++) mx = fmaxf(mx, acc[e]);
        float p[NE], s = 0.f;
        for (int e = 0; e < NE; e++) { p[e] = __expf(acc[e] - mx); s += p[e]; }
        float lse = mx + __logf(s);
        atomicAdd((float*)&meta[M_ZSUM], lse * lse);
        float inv = 1.f / s;
        for (int e = 0; e < NE; e++) {
            p[e] *= inv;
            atomicAdd((float*)&meta[M_PSUM + e], p[e]);
            out[(size_t)OUT_LG + (size_t)t * NE + e] = acc[e];
        }
        int e0 = 0;
        for (int e = 1; e < NE; e++) if (p[e] > p[e0]) e0 = e;
        int e1 = (e0 == 0) ? 1 : 0;
        for (int e = 0; e < NE; e++) if (e != e0 && p[e] > p[e1]) e1 = e;
        float wn = 1.f / (p[e0] + p[e1]);
        tok_e[2 * t] = e0; tok_e[2 * t + 1] = e1;
        tok_w[2 * t] = p[e0] * wn; tok_w[2 * t + 1] = p[e1] * wn;
        atomicAdd(&meta[M_CNT + e0], 1u);
        atomicAdd(&meta[M_CNT + e1], 1u);
    }
}

__global__ void offsets_kernel(uint32_t* meta, float* out) {
    if (threadIdx.x != 0 || blockIdx.x != 0) return;
    uint32_t off = 0, idx = 0;
    for (int e = 0; e < NE; e++) {
        meta[M_AOFF + e] = off;
        uint32_t c = meta[M_CNT + e];
        uint32_t nt = (c + 63) >> 6;
        for (uint32_t j = 0; j < nt && idx < MAX_TILES; j++) {
            meta[M_TE + idx] = e;
            meta[M_TB + idx] = off + j * 64;
            idx++;
        }
        off += nt * 64;
    }
    meta[M_AOFF + NE] = off;
    for (uint32_t j = 0; j < NTOK / 64 && idx < MAX_TILES; j++) {
        meta[M_TE + idx] = NE;
        meta[M_TB + idx] = SH_BASE + j * 64;
        idx++;
    }
    meta[M_NTILE] = idx;
    float aux = 0.f;
    for (int e = 0; e < NE; e++) {
        float tpe = (float)meta[M_CNT + e] / (2.f * NTOK);
        float ppe = ((float*)meta)[M_PSUM + e] / (float)NTOK;
        aux += tpe * ppe;
    }
    out[OUT_AUX] = aux * NE;
    out[OUT_Z] = ((float*)meta)[M_ZSUM] / (float)NTOK;
}

__global__ void fill_kernel(uint32_t* perm) {
    int g = blockIdx.x * 256 + threadIdx.x;
    if (g < NSLOT) perm[g] = (g < SH_BASE) ? 0u : (uint32_t)(g - SH_BASE);
}

__global__ void dispatch_kernel(uint32_t* meta, const int* tok_e,
                                uint32_t* perm, uint32_t* slot_of) {
    int t = blockIdx.x * 256 + threadIdx.x;
    if (t >= NTOK) return;
    for (int k = 0; k < 2; k++) {
        int e = tok_e[2 * t + k] & 7;
        uint32_t pos = atomicAdd(&meta[M_CUR + e], 1u);
        uint32_t slot = meta[M_AOFF + e] + pos;
        if (slot >= NSLOT) slot = 0;
        perm[slot] = (uint32_t)t;
        slot_of[2 * t + k] = slot;
    }
}

// transpose + f32->bf16 convert, 27 matrices of 2M elems: dst[c][r] = (bf16)src[r][c]
__global__ __launch_bounds__(256) void transpose_kernel(
    const float* gw, const float* uw, const float* dw,
    const float* sg, const float* su, const float* sd, char* ws)
{
    int mat = blockIdx.x >> 9, tile = blockIdx.x & 511;
    const float* src; bf16* dst; int R, C;
    const size_t MSZ = (size_t)HID * IDIM;
    if (mat < 8)       { src = gw + mat * MSZ;        dst = (bf16*)(ws + WS_GATET) + mat * MSZ; R = HID;  C = IDIM; }
    else if (mat < 16) { src = uw + (mat - 8) * MSZ;  dst = (bf16*)(ws + WS_UPT) + (mat - 8) * MSZ; R = HID; C = IDIM; }
    else if (mat < 24) { src = dw + (mat - 16) * MSZ; dst = (bf16*)(ws + WS_DOWNT) + (mat - 16) * MSZ; R = IDIM; C = HID; }
    else if (mat == 24){ src = sg; dst = (bf16*)(ws + WS_SGT); R = HID; C = IDIM; }
    else if (mat == 25){ src = su; dst = (bf16*)(ws + WS_SUT); R = HID; C = IDIM; }
    else               { src = sd; dst = (bf16*)(ws + WS_SDT); R = IDIM; C = HID; }
    int tpr = C >> 6;
    int r0 = (tile / tpr) * 64, c0 = (tile % tpr) * 64;
    __shared__ bf16 tl[64][65];
    int tid = threadIdx.x;
#pragma unroll
    for (int it = 0; it < 4; it++) {
        int idx = tid + it * 256;                  // [0,1024)
        int r = idx >> 4, c4 = (idx & 15) * 4;
        f32x4 v = *(const f32x4*)&src[(size_t)(r0 + r) * C + c0 + c4];
#pragma unroll
        for (int j = 0; j < 4; j++) tl[c4 + j][r] = (bf16)v[j];
    }
    __syncthreads();
#pragma unroll
    for (int it = 0; it < 2; it++) {
        int idx = tid + it * 256;                  // [0,512)
        int rr = idx >> 3, c8 = (idx & 7) * 8;
        bf16x8 o;
#pragma unroll
        for (int j = 0; j < 8; j++) o[j] = tl[rr][c8 + j];
        *(bf16x8*)&dst[(size_t)(c0 + rr) * R + r0 + c8] = o;
    }
}

// stage 1: act[slot][i] = silu(x@gateT) * (x@upT), tile 64(M) x 128(N), BK=64
__global__ __launch_bounds__(256) void stage1_kernel(
    const float* __restrict__ x, char* __restrict__ ws)
{
    uint32_t* meta = (uint32_t*)(ws + WS_META);
    int mtile = blockIdx.y;
    int ntile = imin((int)meta[M_NTILE], MAX_TILES);
    if (mtile >= ntile) return;
    int e = imin((int)meta[M_TE + mtile], NE);
    int slot0 = imin((int)meta[M_TB + mtile], NSLOT - 64);
    if (slot0 < 0) slot0 = 0;
    int n0 = blockIdx.x * 128;
    const bf16* Bg = (e < NE) ? (const bf16*)(ws + WS_GATET) + (size_t)e * HID * IDIM
                              : (const bf16*)(ws + WS_SGT);
    const bf16* Bu = (e < NE) ? (const bf16*)(ws + WS_UPT) + (size_t)e * HID * IDIM
                              : (const bf16*)(ws + WS_SUT);
    const uint32_t* perm = (const uint32_t*)(ws + WS_PERM);
    bf16* act = (bf16*)(ws + WS_ACT);

    __shared__ bf16 As[64 * 64];
    __shared__ bf16 Bgs[128 * 64];
    __shared__ bf16 Bus[128 * 64];
    __shared__ int toks[64];
    int tid = threadIdx.x;
    if (tid < 64) toks[tid] = (int)(perm[slot0 + tid] & (NTOK - 1));
    __syncthreads();

    int lane = tid & 63, wv = tid >> 6;
    int q = lane >> 4, m = lane & 15;
    f32x4 zero4 = {0.f, 0.f, 0.f, 0.f};
    f32x4 accg[4][2], accu[4][2];
#pragma unroll
    for (int a = 0; a < 4; a++)
#pragma unroll
        for (int b = 0; b < 2; b++) { accg[a][b] = zero4; accu[a][b] = zero4; }

    for (int k0 = 0; k0 < HID; k0 += 64) {
        // A: f32 global -> bf16 LDS (64 rows x 64 cols)
#pragma unroll
        for (int it = 0; it < 4; it++) {
            int idx = tid + it * 256;              // [0,1024)
            int r = idx >> 4, c4 = (idx & 15) * 4;
            f32x4 v = *(const f32x4*)&x[(size_t)toks[r] * HID + k0 + c4];
            bf16x4 b;
#pragma unroll
            for (int j = 0; j < 4; j++) b[j] = (bf16)v[j];
            *(bf16x4*)&As[r * 64 + c4] = b;
        }
        // B: bf16 ws -> LDS (128 rows x 64 cols, two matrices)
#pragma unroll
        for (int it = 0; it < 4; it++) {
            int idx = tid + it * 256;
            int r = idx >> 3, c = (idx & 7) * 8;
            *(bf16x8*)&Bgs[r * 64 + c] = *(const bf16x8*)&Bg[(size_t)(n0 + r) * HID + k0 + c];
            *(bf16x8*)&Bus[r * 64 + c] = *(const bf16x8*)&Bu[(size_t)(n0 + r) * HID + k0 + c];
        }
        __syncthreads();
#pragma unroll
        for (int kk = 0; kk < 64; kk += 32) {
            bf16x8 af[4];
#pragma unroll
            for (int m4 = 0; m4 < 4; m4++)
                af[m4] = *(bf16x8*)&As[(m4 * 16 + m) * 64 + kk + q * 8];
#pragma unroll
            for (int nt = 0; nt < 2; nt++) {
                int n = wv * 32 + nt * 16 + m;
                bf16x8 bg = *(bf16x8*)&Bgs[n * 64 + kk + q * 8];
                bf16x8 bu = *(bf16x8*)&Bus[n * 64 + kk + q * 8];
#pragma unroll
                for (int m4 = 0; m4 < 4; m4++) {
                    accg[m4][nt] = __builtin_amdgcn_mfma_f32_16x16x32_bf16(af[m4], bg, accg[m4][nt], 0, 0, 0);
                    accu[m4][nt] = __builtin_amdgcn_mfma_f32_16x16x32_bf16(af[m4], bu, accu[m4][nt], 0, 0, 0);
                }
            }
        }
        __syncthreads();
    }
#pragma unroll
    for (int m4 = 0; m4 < 4; m4++)
#pragma unroll
        for (int nt = 0; nt < 2; nt++)
#pragma unroll
            for (int r = 0; r < 4; r++) {
                float g = accg[m4][nt][r], u = accu[m4][nt][r];
                float v = g / (1.f + __expf(-g)) * u;
                int slot = slot0 + m4 * 16 + q * 4 + r;
                int col = n0 + wv * 32 + nt * 16 + m;
                act[(size_t)slot * IDIM + col] = (bf16)v;
            }
}

// stage 2: down_out[slot][h] = act @ downT, tile 64 x 128, BK=64, K=2048
__global__ __launch_bounds__(256) void stage2_kernel(char* __restrict__ ws)
{
    uint32_t* meta = (uint32_t*)(ws + WS_META);
    int mtile = blockIdx.y;
    int ntile = imin((int)meta[M_NTILE], MAX_TILES);
    if (mtile >= ntile) return;
    int e = imin((int)meta[M_TE + mtile], NE);
    int slot0 = imin((int)meta[M_TB + mtile], NSLOT - 64);
    if (slot0 < 0) slot0 = 0;
    int n0 = blockIdx.x * 128;
    const bf16* B = (e < NE) ? (const bf16*)(ws + WS_DOWNT) + (size_t)e * HID * IDIM
                             : (const bf16*)(ws + WS_SDT);
    const bf16* act = (const bf16*)(ws + WS_ACT);
    bf16* dout = (bf16*)(ws + WS_DOUT);

    __shared__ bf16 As[64 * 64];
    __shared__ bf16 Bs[128 * 64];
    int tid = threadIdx.x;
    int lane = tid & 63, wv = tid >> 6;
    int q = lane >> 4, m = lane & 15;
    f32x4 zero4 = {0.f, 0.f, 0.f, 0.f};
    f32x4 acc[4][2];
#pragma unroll
    for (int a = 0; a < 4; a++)
#pragma unroll
        for (int b = 0; b < 2; b++) acc[a][b] = zero4;

    for (int k0 = 0; k0 < IDIM; k0 += 64) {
#pragma unroll
        for (int it = 0; it < 2; it++) {
            int idx = tid + it * 256;
            int r = idx >> 3, c = (idx & 7) * 8;
            *(bf16x8*)&As[r * 64 + c] = *(const bf16x8*)&act[(size_t)(slot0 + r) * IDIM + k0 + c];
        }
#pragma unroll
        for (int it = 0; it < 4; it++) {
            int idx = tid + it * 256;
            int r = idx >> 3, c = (idx & 7) * 8;
            *(bf16x8*)&Bs[r * 64 + c] = *(const bf16x8*)&B[(size_t)(n0 + r) * IDIM + k0 + c];
        }
        __syncthreads();
#pragma unroll
        for (int kk = 0; kk < 64; kk += 32) {
            bf16x8 af[4];
#pragma unroll
            for (int m4 = 0; m4 < 4; m4++)
                af[m4] = *(bf16x8*)&As[(m4 * 16 + m) * 64 + kk + q * 8];
#pragma unroll
            for (int nt = 0; nt < 2; nt++) {
                int n = wv * 32 + nt * 16 + m;
                bf16x8 bfr = *(bf16x8*)&Bs[n * 64 + kk + q * 8];
#pragma unroll
                for (int m4 = 0; m4 < 4; m4++)
                    acc[m4][nt] = __builtin_amdgcn_mfma_f32_16x16x32_bf16(af[m4], bfr, acc[m4][nt], 0, 0, 0);
            }
        }
        __syncthreads();
    }
#pragma unroll
    for (int m4 = 0; m4 < 4; m4++)
#pragma unroll
        for (int nt = 0; nt < 2; nt++)
#pragma unroll
            for (int r = 0; r < 4; r++) {
                int slot = slot0 + m4 * 16 + q * 4 + r;
                int col = n0 + wv * 32 + nt * 16 + m;
                dout[(size_t)slot * HID + col] = (bf16)acc[m4][nt][r];
            }
}

__global__ __launch_bounds__(256) void combine_kernel(char* __restrict__ ws, float* __restrict__ out)
{
    int g = blockIdx.x * 256 + threadIdx.x;
    int t = g >> 7;
    int hc = (g & 127) * 8;
    const uint32_t* slot_of = (const uint32_t*)(ws + WS_SLOTOF);
    const float* tok_w = (const float*)(ws + WS_TOKW);
    const bf16* dout = (const bf16*)(ws + WS_DOUT);
    uint32_t s0 = slot_of[2 * t], s1 = slot_of[2 * t + 1];
    if (s0 >= NSLOT) s0 = 0;
    if (s1 >= NSLOT) s1 = 0;
    float w0 = tok_w[2 * t], w1 = tok_w[2 * t + 1];
    bf16x8 a = *(const bf16x8*)&dout[(size_t)s0 * HID + hc];
    bf16x8 b = *(const bf16x8*)&dout[(size_t)s1 * HID + hc];
    bf16x8 c = *(const bf16x8*)&dout[(size_t)(SH_BASE + t) * HID + hc];
    f32x4 o0, o1;
#pragma unroll
    for (int j = 0; j < 4; j++)
        o0[j] = w0 * (float)a[j] + w1 * (float)b[j] + (float)c[j];
#pragma unroll
    for (int j = 0; j < 4; j++)
        o1[j] = w0 * (float)a[j + 4] + w1 * (float)b[j + 4] + (float)c[j + 4];
    *(f32x4*)&out[(size_t)t * HID + hc] = o0;
    *(f32x4*)&out[(size_t)t * HID + hc + 4] = o1;
}

extern "C" void kernel_launch(void* const* d_in, const int* in_sizes, int n_in,
                              void* d_out, int out_size, void* d_ws, size_t ws_size,
                              hipStream_t stream) {
    const float* x  = (const float*)d_in[0];
    const float* rw = (const float*)d_in[1];
    const float* gw = (const float*)d_in[2];
    const float* uw = (const float*)d_in[3];
    const float* dw = (const float*)d_in[4];
    const float* sg = (const float*)d_in[5];
    const float* su = (const float*)d_in[6];
    const float* sd = (const float*)d_in[7];
    float* out = (float*)d_out;
    char* ws = (char*)d_ws;
    uint32_t* meta = (uint32_t*)(ws + WS_META);
    uint32_t* perm = (uint32_t*)(ws + WS_PERM);
    int* tok_e = (int*)(ws + WS_TOKE);
    float* tok_w = (float*)(ws + WS_TOKW);
    uint32_t* slot_of = (uint32_t*)(ws + WS_SLOTOF);

    hipLaunchKernelGGL(zero_kernel, dim3(1), dim3(64), 0, stream, meta);
    hipLaunchKernelGGL(router_kernel, dim3(NTOK / 4), dim3(256), 0, stream,
                       x, rw, out, meta, tok_e, tok_w);
    hipLaunchKernelGGL(offsets_kernel, dim3(1), dim3(64), 0, stream, meta, out);
    hipLaunchKernelGGL(fill_kernel, dim3((NSLOT + 255) / 256), dim3(256), 0, stream, perm);
    hipLaunchKernelGGL(dispatch_kernel, dim3(NTOK / 256), dim3(256), 0, stream,
                       meta, tok_e, perm, slot_of);
    hipLaunchKernelGGL(transpose_kernel, dim3(27 * 512), dim3(256), 0, stream,
                       gw, uw, dw, sg, su, sd, ws);
    hipLaunchKernelGGL(stage1_kernel, dim3(IDIM / 128, MAX_TILES), dim3(256), 0, stream, x, ws);
    hipLaunchKernelGGL(stage2_kernel, dim3(HID / 128, MAX_TILES), dim3(256), 0, stream, ws);
    hipLaunchKernelGGL(combine_kernel, dim3(NTOK * HID / 8 / 256), dim3(256), 0, stream, ws, out);
}

// Round 4
// 638.684 us; speedup vs baseline: 1.7521x; 1.7521x over previous
//
#include <hip/hip_runtime.h>
#include <hip/hip_bf16.h>
#include <stdint.h>
#include <stddef.h>

typedef __bf16 bf16;
typedef __bf16 bf16x8 __attribute__((ext_vector_type(8)));
typedef __bf16 bf16x4 __attribute__((ext_vector_type(4)));
typedef float f32x4 __attribute__((ext_vector_type(4)));

#define HID 1024
#define IDIM 2048
#define NE 8
#define NTOK 4096
#define NSLOT 12800
#define SH_BASE 8704
#define MAX_TILES 200

// ---- workspace byte offsets ----
#define WS_META    0
#define WS_PERM    4096              // u32[12800]
#define WS_TOKE    55296             // i32[8192]
#define WS_TOKW    88064             // f32[8192]
#define WS_SLOTOF  120832            // u32[8192]
#define WS_GATET   153600            // bf16[8][2048][1024]
#define WS_UPT     33708032
#define WS_DOWNT   67262464          // bf16[8][1024][2048]
#define WS_SGT     100816896         // bf16[2048][1024]
#define WS_SUT     105011200
#define WS_SDT     109205504         // bf16[1024][2048]
#define WS_ACT     113399808         // bf16[12800][2048]
#define WS_DOUT    165828608         // bf16[12800][1024]

// meta u32-index layout
#define M_CNT 0
#define M_CUR 8
#define M_PSUM 16
#define M_ZSUM 24
#define M_AOFF 32
#define M_NTILE 48
#define M_TE 64
#define M_TB 320

#define OUT_AUX 4194304
#define OUT_Z   4194305
#define OUT_LG  4194306

__device__ __forceinline__ int imin(int a, int b) { return a < b ? a : b; }

__global__ void zero_kernel(uint32_t* meta) {
    if (threadIdx.x < 32) meta[threadIdx.x] = 0;
}

// 16 tokens per 1024-thread block; block-level LDS aggregation -> 17 global
// atomics per block (was 9 per token). Same-address atomic serialization was
// 480us of the round-3 runtime.
__global__ __launch_bounds__(1024) void router_kernel(
    const float* __restrict__ x, const float* __restrict__ rw,
    float* __restrict__ out, uint32_t* meta, int* tok_e, float* tok_w)
{
    __shared__ float s_psum[NE];
    __shared__ float s_zsum;
    __shared__ uint32_t s_cnt[NE];
    int tid = threadIdx.x;
    if (tid < NE) { s_psum[tid] = 0.f; s_cnt[tid] = 0u; }
    if (tid == NE) s_zsum = 0.f;
    __syncthreads();

    int lane = tid & 63, wv = tid >> 6;
    int t = blockIdx.x * 16 + wv;
    float acc[NE];
#pragma unroll
    for (int e = 0; e < NE; e++) acc[e] = 0.f;
#pragma unroll
    for (int it = 0; it < 4; it++) {
        int h0 = (lane + it * 64) * 4;
        f32x4 xv = *(const f32x4*)&x[(size_t)t * HID + h0];
#pragma unroll
        for (int j = 0; j < 4; j++) {
            float xf = xv[j];
            const float* wrow = rw + (size_t)(h0 + j) * NE;
            f32x4 w0 = *(const f32x4*)wrow;
            f32x4 w1 = *(const f32x4*)(wrow + 4);
#pragma unroll
            for (int e = 0; e < 4; e++) { acc[e] += xf * w0[e]; acc[e + 4] += xf * w1[e]; }
        }
    }
#pragma unroll
    for (int off = 32; off >= 1; off >>= 1)
#pragma unroll
        for (int e = 0; e < NE; e++) acc[e] += __shfl_xor(acc[e], off);

    if (lane == 0) {
        float mx = acc[0];
        for (int e = 1; e < NE; e++) mx = fmaxf(mx, acc[e]);
        float p[NE], s = 0.f;
        for (int e = 0; e < NE; e++) { p[e] = __expf(acc[e] - mx); s += p[e]; }
        float lse = mx + __logf(s);
        atomicAdd(&s_zsum, lse * lse);
        float inv = 1.f / s;
        for (int e = 0; e < NE; e++) {
            p[e] *= inv;
            atomicAdd(&s_psum[e], p[e]);
            out[(size_t)OUT_LG + (size_t)t * NE + e] = acc[e];
        }
        int e0 = 0;
        for (int e = 1; e < NE; e++) if (p[e] > p[e0]) e0 = e;
        int e1 = (e0 == 0) ? 1 : 0;
        for (int e = 0; e < NE; e++) if (e != e0 && p[e] > p[e1]) e1 = e;
        float wn = 1.f / (p[e0] + p[e1]);
        tok_e[2 * t] = e0; tok_e[2 * t + 1] = e1;
        tok_w[2 * t] = p[e0] * wn; tok_w[2 * t + 1] = p[e1] * wn;
        atomicAdd(&s_cnt[e0], 1u);
        atomicAdd(&s_cnt[e1], 1u);
    }
    __syncthreads();
    if (tid < NE) {
        atomicAdd((float*)&meta[M_PSUM + tid], s_psum[tid]);
        atomicAdd(&meta[M_CNT + tid], s_cnt[tid]);
    }
    if (tid == NE) atomicAdd((float*)&meta[M_ZSUM], s_zsum);
}

__global__ void offsets_kernel(uint32_t* meta, float* out) {
    if (threadIdx.x != 0 || blockIdx.x != 0) return;
    uint32_t off = 0, idx = 0;
    for (int e = 0; e < NE; e++) {
        meta[M_AOFF + e] = off;
        uint32_t c = meta[M_CNT + e];
        uint32_t nt = (c + 63) >> 6;
        for (uint32_t j = 0; j < nt && idx < MAX_TILES; j++) {
            meta[M_TE + idx] = e;
            meta[M_TB + idx] = off + j * 64;
            idx++;
        }
        off += nt * 64;
    }
    meta[M_AOFF + NE] = off;
    for (uint32_t j = 0; j < NTOK / 64 && idx < MAX_TILES; j++) {
        meta[M_TE + idx] = NE;
        meta[M_TB + idx] = SH_BASE + j * 64;
        idx++;
    }
    meta[M_NTILE] = idx;
    float aux = 0.f;
    for (int e = 0; e < NE; e++) {
        float tpe = (float)meta[M_CNT + e] / (2.f * NTOK);
        float ppe = ((float*)meta)[M_PSUM + e] / (float)NTOK;
        aux += tpe * ppe;
    }
    out[OUT_AUX] = aux * NE;
    out[OUT_Z] = ((float*)meta)[M_ZSUM] / (float)NTOK;
}

__global__ void fill_kernel(uint32_t* perm) {
    int g = blockIdx.x * 256 + threadIdx.x;
    if (g < NSLOT) perm[g] = (g < SH_BASE) ? 0u : (uint32_t)(g - SH_BASE);
}

// wave-aggregated slot assignment: one atomic per (wave, expert) not per token
__global__ void dispatch_kernel(uint32_t* meta, const int* tok_e,
                                uint32_t* perm, uint32_t* slot_of) {
    int t = blockIdx.x * 256 + threadIdx.x;
    int lane = threadIdx.x & 63;
    for (int k = 0; k < 2; k++) {
        int e = tok_e[2 * t + k] & 7;
#pragma unroll
        for (int ee = 0; ee < NE; ee++) {
            bool mine = (e == ee);
            unsigned long long mask = __ballot(mine);
            if (mask == 0ull) continue;
            int leader = __ffsll((unsigned long long)mask) - 1;
            uint32_t wbase = 0;
            if (lane == leader)
                wbase = atomicAdd(&meta[M_CUR + ee], (uint32_t)__popcll(mask));
            wbase = __shfl(wbase, leader);
            if (mine) {
                uint32_t myrank = (uint32_t)__popcll(mask & ((1ull << lane) - 1ull));
                uint32_t slot = meta[M_AOFF + ee] + wbase + myrank;
                if (slot >= NSLOT) slot = 0;
                perm[slot] = (uint32_t)t;
                slot_of[2 * t + k] = slot;
            }
        }
    }
}

// transpose + f32->bf16 convert, 27 matrices of 2M elems: dst[c][r] = (bf16)src[r][c]
__global__ __launch_bounds__(256) void transpose_kernel(
    const float* gw, const float* uw, const float* dw,
    const float* sg, const float* su, const float* sd, char* ws)
{
    int mat = blockIdx.x >> 9, tile = blockIdx.x & 511;
    const float* src; bf16* dst; int R, C;
    const size_t MSZ = (size_t)HID * IDIM;
    if (mat < 8)       { src = gw + mat * MSZ;        dst = (bf16*)(ws + WS_GATET) + mat * MSZ; R = HID;  C = IDIM; }
    else if (mat < 16) { src = uw + (mat - 8) * MSZ;  dst = (bf16*)(ws + WS_UPT) + (mat - 8) * MSZ; R = HID; C = IDIM; }
    else if (mat < 24) { src = dw + (mat - 16) * MSZ; dst = (bf16*)(ws + WS_DOWNT) + (mat - 16) * MSZ; R = IDIM; C = HID; }
    else if (mat == 24){ src = sg; dst = (bf16*)(ws + WS_SGT); R = HID; C = IDIM; }
    else if (mat == 25){ src = su; dst = (bf16*)(ws + WS_SUT); R = HID; C = IDIM; }
    else               { src = sd; dst = (bf16*)(ws + WS_SDT); R = IDIM; C = HID; }
    int tpr = C >> 6;
    int r0 = (tile / tpr) * 64, c0 = (tile % tpr) * 64;
    __shared__ bf16 tl[64][65];
    int tid = threadIdx.x;
#pragma unroll
    for (int it = 0; it < 4; it++) {
        int idx = tid + it * 256;                  // [0,1024)
        int r = idx >> 4, c4 = (idx & 15) * 4;
        f32x4 v = *(const f32x4*)&src[(size_t)(r0 + r) * C + c0 + c4];
#pragma unroll
        for (int j = 0; j < 4; j++) tl[c4 + j][r] = (bf16)v[j];
    }
    __syncthreads();
#pragma unroll
    for (int it = 0; it < 2; it++) {
        int idx = tid + it * 256;                  // [0,512)
        int rr = idx >> 3, c8 = (idx & 7) * 8;
        bf16x8 o;
#pragma unroll
        for (int j = 0; j < 8; j++) o[j] = tl[rr][c8 + j];
        *(bf16x8*)&dst[(size_t)(c0 + rr) * R + r0 + c8] = o;
    }
}

// stage 1: act[slot][i] = silu(x@gateT) * (x@upT), tile 64(M) x 128(N), BK=64
__global__ __launch_bounds__(256) void stage1_kernel(
    const float* __restrict__ x, char* __restrict__ ws)
{
    uint32_t* meta = (uint32_t*)(ws + WS_META);
    int mtile = blockIdx.y;
    int ntile = imin((int)meta[M_NTILE], MAX_TILES);
    if (mtile >= ntile) return;
    int e = imin((int)meta[M_TE + mtile], NE);
    int slot0 = imin((int)meta[M_TB + mtile], NSLOT - 64);
    if (slot0 < 0) slot0 = 0;
    int n0 = blockIdx.x * 128;
    const bf16* Bg = (e < NE) ? (const bf16*)(ws + WS_GATET) + (size_t)e * HID * IDIM
                              : (const bf16*)(ws + WS_SGT);
    const bf16* Bu = (e < NE) ? (const bf16*)(ws + WS_UPT) + (size_t)e * HID * IDIM
                              : (const bf16*)(ws + WS_SUT);
    const uint32_t* perm = (const uint32_t*)(ws + WS_PERM);
    bf16* act = (bf16*)(ws + WS_ACT);

    __shared__ bf16 As[64 * 64];
    __shared__ bf16 Bgs[128 * 64];
    __shared__ bf16 Bus[128 * 64];
    __shared__ int toks[64];
    int tid = threadIdx.x;
    if (tid < 64) toks[tid] = (int)(perm[slot0 + tid] & (NTOK - 1));
    __syncthreads();

    int lane = tid & 63, wv = tid >> 6;
    int q = lane >> 4, m = lane & 15;
    f32x4 zero4 = {0.f, 0.f, 0.f, 0.f};
    f32x4 accg[4][2], accu[4][2];
#pragma unroll
    for (int a = 0; a < 4; a++)
#pragma unroll
        for (int b = 0; b < 2; b++) { accg[a][b] = zero4; accu[a][b] = zero4; }

    for (int k0 = 0; k0 < HID; k0 += 64) {
        // A: f32 global -> bf16 LDS (64 rows x 64 cols)
#pragma unroll
        for (int it = 0; it < 4; it++) {
            int idx = tid + it * 256;              // [0,1024)
            int r = idx >> 4, c4 = (idx & 15) * 4;
            f32x4 v = *(const f32x4*)&x[(size_t)toks[r] * HID + k0 + c4];
            bf16x4 b;
#pragma unroll
            for (int j = 0; j < 4; j++) b[j] = (bf16)v[j];
            *(bf16x4*)&As[r * 64 + c4] = b;
        }
        // B: bf16 ws -> LDS (128 rows x 64 cols, two matrices)
#pragma unroll
        for (int it = 0; it < 4; it++) {
            int idx = tid + it * 256;
            int r = idx >> 3, c = (idx & 7) * 8;
            *(bf16x8*)&Bgs[r * 64 + c] = *(const bf16x8*)&Bg[(size_t)(n0 + r) * HID + k0 + c];
            *(bf16x8*)&Bus[r * 64 + c] = *(const bf16x8*)&Bu[(size_t)(n0 + r) * HID + k0 + c];
        }
        __syncthreads();
#pragma unroll
        for (int kk = 0; kk < 64; kk += 32) {
            bf16x8 af[4];
#pragma unroll
            for (int m4 = 0; m4 < 4; m4++)
                af[m4] = *(bf16x8*)&As[(m4 * 16 + m) * 64 + kk + q * 8];
#pragma unroll
            for (int nt = 0; nt < 2; nt++) {
                int n = wv * 32 + nt * 16 + m;
                bf16x8 bg = *(bf16x8*)&Bgs[n * 64 + kk + q * 8];
                bf16x8 bu = *(bf16x8*)&Bus[n * 64 + kk + q * 8];
#pragma unroll
                for (int m4 = 0; m4 < 4; m4++) {
                    accg[m4][nt] = __builtin_amdgcn_mfma_f32_16x16x32_bf16(af[m4], bg, accg[m4][nt], 0, 0, 0);
                    accu[m4][nt] = __builtin_amdgcn_mfma_f32_16x16x32_bf16(af[m4], bu, accu[m4][nt], 0, 0, 0);
                }
            }
        }
        __syncthreads();
    }
#pragma unroll
    for (int m4 = 0; m4 < 4; m4++)
#pragma unroll
        for (int nt = 0; nt < 2; nt++)
#pragma unroll
            for (int r = 0; r < 4; r++) {
                float g = accg[m4][nt][r], u = accu[m4][nt][r];
                float v = g / (1.f + __expf(-g)) * u;
                int slot = slot0 + m4 * 16 + q * 4 + r;
                int col = n0 + wv * 32 + nt * 16 + m;
                act[(size_t)slot * IDIM + col] = (bf16)v;
            }
}

// stage 2: down_out[slot][h] = act @ downT, tile 64 x 128, BK=64, K=2048
__global__ __launch_bounds__(256) void stage2_kernel(char* __restrict__ ws)
{
    uint32_t* meta = (uint32_t*)(ws + WS_META);
    int mtile = blockIdx.y;
    int ntile = imin((int)meta[M_NTILE], MAX_TILES);
    if (mtile >= ntile) return;
    int e = imin((int)meta[M_TE + mtile], NE);
    int slot0 = imin((int)meta[M_TB + mtile], NSLOT - 64);
    if (slot0 < 0) slot0 = 0;
    int n0 = blockIdx.x * 128;
    const bf16* B = (e < NE) ? (const bf16*)(ws + WS_DOWNT) + (size_t)e * HID * IDIM
                             : (const bf16*)(ws + WS_SDT);
    const bf16* act = (const bf16*)(ws + WS_ACT);
    bf16* dout = (bf16*)(ws + WS_DOUT);

    __shared__ bf16 As[64 * 64];
    __shared__ bf16 Bs[128 * 64];
    int tid = threadIdx.x;
    int lane = tid & 63, wv = tid >> 6;
    int q = lane >> 4, m = lane & 15;
    f32x4 zero4 = {0.f, 0.f, 0.f, 0.f};
    f32x4 acc[4][2];
#pragma unroll
    for (int a = 0; a < 4; a++)
#pragma unroll
        for (int b = 0; b < 2; b++) acc[a][b] = zero4;

    for (int k0 = 0; k0 < IDIM; k0 += 64) {
#pragma unroll
        for (int it = 0; it < 2; it++) {
            int idx = tid + it * 256;
            int r = idx >> 3, c = (idx & 7) * 8;
            *(bf16x8*)&As[r * 64 + c] = *(const bf16x8*)&act[(size_t)(slot0 + r) * IDIM + k0 + c];
        }
#pragma unroll
        for (int it = 0; it < 4; it++) {
            int idx = tid + it * 256;
            int r = idx >> 3, c = (idx & 7) * 8;
            *(bf16x8*)&Bs[r * 64 + c] = *(const bf16x8*)&B[(size_t)(n0 + r) * IDIM + k0 + c];
        }
        __syncthreads();
#pragma unroll
        for (int kk = 0; kk < 64; kk += 32) {
            bf16x8 af[4];
#pragma unroll
            for (int m4 = 0; m4 < 4; m4++)
                af[m4] = *(bf16x8*)&As[(m4 * 16 + m) * 64 + kk + q * 8];
#pragma unroll
            for (int nt = 0; nt < 2; nt++) {
                int n = wv * 32 + nt * 16 + m;
                bf16x8 bfr = *(bf16x8*)&Bs[n * 64 + kk + q * 8];
#pragma unroll
                for (int m4 = 0; m4 < 4; m4++)
                    acc[m4][nt] = __builtin_amdgcn_mfma_f32_16x16x32_bf16(af[m4], bfr, acc[m4][nt], 0, 0, 0);
            }
        }
        __syncthreads();
    }
#pragma unroll
    for (int m4 = 0; m4 < 4; m4++)
#pragma unroll
        for (int nt = 0; nt < 2; nt++)
#pragma unroll
            for (int r = 0; r < 4; r++) {
                int slot = slot0 + m4 * 16 + q * 4 + r;
                int col = n0 + wv * 32 + nt * 16 + m;
                dout[(size_t)slot * HID + col] = (bf16)acc[m4][nt][r];
            }
}

__global__ __launch_bounds__(256) void combine_kernel(char* __restrict__ ws, float* __restrict__ out)
{
    int g = blockIdx.x * 256 + threadIdx.x;
    int t = g >> 7;
    int hc = (g & 127) * 8;
    const uint32_t* slot_of = (const uint32_t*)(ws + WS_SLOTOF);
    const float* tok_w = (const float*)(ws + WS_TOKW);
    const bf16* dout = (const bf16*)(ws + WS_DOUT);
    uint32_t s0 = slot_of[2 * t], s1 = slot_of[2 * t + 1];
    if (s0 >= NSLOT) s0 = 0;
    if (s1 >= NSLOT) s1 = 0;
    float w0 = tok_w[2 * t], w1 = tok_w[2 * t + 1];
    bf16x8 a = *(const bf16x8*)&dout[(size_t)s0 * HID + hc];
    bf16x8 b = *(const bf16x8*)&dout[(size_t)s1 * HID + hc];
    bf16x8 c = *(const bf16x8*)&dout[(size_t)(SH_BASE + t) * HID + hc];
    f32x4 o0, o1;
#pragma unroll
    for (int j = 0; j < 4; j++)
        o0[j] = w0 * (float)a[j] + w1 * (float)b[j] + (float)c[j];
#pragma unroll
    for (int j = 0; j < 4; j++)
        o1[j] = w0 * (float)a[j + 4] + w1 * (float)b[j + 4] + (float)c[j + 4];
    *(f32x4*)&out[(size_t)t * HID + hc] = o0;
    *(f32x4*)&out[(size_t)t * HID + hc + 4] = o1;
}

extern "C" void kernel_launch(void* const* d_in, const int* in_sizes, int n_in,
                              void* d_out, int out_size, void* d_ws, size_t ws_size,
                              hipStream_t stream) {
    const float* x  = (const float*)d_in[0];
    const float* rw = (const float*)d_in[1];
    const float* gw = (const float*)d_in[2];
    const float* uw = (const float*)d_in[3];
    const float* dw = (const float*)d_in[4];
    const float* sg = (const float*)d_in[5];
    const float* su = (const float*)d_in[6];
    const float* sd = (const float*)d_in[7];
    float* out = (float*)d_out;
    char* ws = (char*)d_ws;
    uint32_t* meta = (uint32_t*)(ws + WS_META);
    uint32_t* perm = (uint32_t*)(ws + WS_PERM);
    int* tok_e = (int*)(ws + WS_TOKE);
    float* tok_w = (float*)(ws + WS_TOKW);
    uint32_t* slot_of = (uint32_t*)(ws + WS_SLOTOF);

    hipLaunchKernelGGL(zero_kernel, dim3(1), dim3(64), 0, stream, meta);
    hipLaunchKernelGGL(router_kernel, dim3(NTOK / 16), dim3(1024), 0, stream,
                       x, rw, out, meta, tok_e, tok_w);
    hipLaunchKernelGGL(offsets_kernel, dim3(1), dim3(64), 0, stream, meta, out);
    hipLaunchKernelGGL(fill_kernel, dim3((NSLOT + 255) / 256), dim3(256), 0, stream, perm);
    hipLaunchKernelGGL(dispatch_kernel, dim3(NTOK / 256), dim3(256), 0, stream,
                       meta, tok_e, perm, slot_of);
    hipLaunchKernelGGL(transpose_kernel, dim3(27 * 512), dim3(256), 0, stream,
                       gw, uw, dw, sg, su, sd, ws);
    hipLaunchKernelGGL(stage1_kernel, dim3(IDIM / 128, MAX_TILES), dim3(256), 0, stream, x, ws);
    hipLaunchKernelGGL(stage2_kernel, dim3(HID / 128, MAX_TILES), dim3(256), 0, stream, ws);
    hipLaunchKernelGGL(combine_kernel, dim3(NTOK * HID / 8 / 256), dim3(256), 0, stream, ws, out);
}